// Round 17
// baseline (251.454 us; speedup 1.0000x reference)
//
#include <hip/hip_runtime.h>
#include <hip/hip_bf16.h>
#include <math.h>

#define DIM 128

typedef __attribute__((ext_vector_type(8))) short bf16x8;
typedef __attribute__((ext_vector_type(4))) float f32x4;

union FragU { bf16x8 v; __hip_bfloat162 h[4]; };

// RNE float -> bf16 bits
static __device__ __forceinline__ ushort f2bf(float f) {
    unsigned u = __float_as_uint(f);
    u += 0x7FFFu + ((u >> 16) & 1u);
    return (ushort)(u >> 16);
}

// async global -> LDS, 16B per lane (lds dest wave-uniform base + lane*16)
typedef __attribute__((address_space(1))) const unsigned GASp;
typedef __attribute__((address_space(3))) unsigned LASp;
static __device__ __forceinline__ void gll16(const void* g, void* l) {
    __builtin_amdgcn_global_load_lds((GASp*)g, (LASp*)l, 16, 0, 0);
}

// stage 16 rows x 128 f32 (8KB); source pre-swizzled: LDS slot (r,x) holds
// emb 16B-chunk (r, x ^ (r&7))
static __device__ __forceinline__ void stage16(float* buf, const float* emb,
                                               long row0, long Tm1, int lane) {
    #pragma unroll
    for (int i = 0; i < 8; ++i) {
        int s = i * 64 + lane;
        int r = s >> 5, x = s & 31;
        long gr = row0 + r; gr = (gr > Tm1) ? Tm1 : gr;
        gll16(emb + gr * 128 + ((x ^ (r & 7)) << 2), (char*)buf + i * 1024);
    }
}

// ---------------- Phase 0: exclusive scan + uniformity flag ----------------
__global__ __launch_bounds__(1024) void scan_kernel(const int* __restrict__ lengths,
                                                    int* __restrict__ offsets, int batch,
                                                    int* __restrict__ uniflag) {
    __shared__ int tsum[1024];
    __shared__ int ok;
    int tid = threadIdx.x;
    if (tid == 0) ok = 1;
    int L0 = lengths[0];
    int per = (batch + 1023) >> 10;
    int start = tid * per;
    int s = 0;
    int loc = 1;
    for (int i = 0; i < per; ++i) {
        int idx = start + i;
        if (idx < batch) {
            int l = lengths[idx];
            s += l;
            if (l != L0) loc = 0;
        }
    }
    tsum[tid] = s;
    __syncthreads();
    if (!loc) atomicAnd(&ok, 0);
    for (int off = 1; off < 1024; off <<= 1) {
        int v = (tid >= off) ? tsum[tid - off] : 0;
        __syncthreads();
        tsum[tid] += v;
        __syncthreads();
    }
    int base = (tid == 0) ? 0 : tsum[tid - 1];
    for (int i = 0; i < per; ++i) {
        int idx = start + i;
        if (idx < batch) { offsets[idx] = base; base += lengths[idx]; }
    }
    __syncthreads();
    if (tid == 0) uniflag[0] = ok;
}

// ---- one 16-row chunk. Buffer is dead after the A-frag ds_reads, so the
// restage (stage_row >= 0) issues at the TOP, right after lgkmcnt(0).
// Pool accumulates w_l * bf16decode(a[kc]) into registers — zero pool mem ops.
static __device__ __forceinline__ void chunk_body(
        float* __restrict__ bufc, int cv, int lane, int lr, int lg,
        long stage_row, const float* __restrict__ emb, long Tm1,
        const bf16x8 (&bfrag)[8][4],
        const float (&b1r)[8], const float (&w2r)[8],
        float& r_ref, float& Sp, float (&pool)[4][8]) {
    // A-frags: swizzled ds_read_b128 pairs + cvt to bf16
    bf16x8 a[4];
    #pragma unroll
    for (int kc = 0; kc < 4; ++kc) {
        int c0 = kc * 8 + lg * 2;
        float4 q0 = *(const float4*)&bufc[(lr * 32 + (c0 ^ (lr & 7))) * 4];
        float4 q1 = *(const float4*)&bufc[(lr * 32 + ((c0 + 1) ^ (lr & 7))) * 4];
        FragU f;
        f.h[0] = __float22bfloat162_rn(make_float2(q0.x, q0.y));
        f.h[1] = __float22bfloat162_rn(make_float2(q0.z, q0.w));
        f.h[2] = __float22bfloat162_rn(make_float2(q1.x, q1.y));
        f.h[3] = __float22bfloat162_rn(make_float2(q1.z, q1.w));
        a[kc] = f.v;
    }
    // buffer fully consumed -> restage it NOW (prefetch distance ~2 chunks)
    asm volatile("s_waitcnt lgkmcnt(0)" ::: "memory");
    if (stage_row >= 0) stage16(bufc, emb, stage_row, Tm1, lane);

    // MFMA: scores for these 16 rows (C: col=lane&15, row=lg*4+reg)
    f32x4 acc[8];
    #pragma unroll
    for (int ct = 0; ct < 8; ++ct) acc[ct] = (f32x4)(0.f);
    #pragma unroll
    for (int ct = 0; ct < 8; ++ct)
        #pragma unroll
        for (int kc = 0; kc < 4; ++kc)
            acc[ct] = __builtin_amdgcn_mfma_f32_16x16x32_bf16(a[kc], bfrag[ct][kc], acc[ct], 0, 0, 0);

    // epilogue: rowsum of relu(acc+b1)*W2 over 16 col-lanes (4 rounds)
    float p[4];
    #pragma unroll
    for (int reg = 0; reg < 4; ++reg) {
        float s = 0.f;
        #pragma unroll
        for (int ct = 0; ct < 8; ++ct) {
            float h = acc[ct][reg] + b1r[ct];
            h = fmaxf(h, 0.f);
            s = fmaf(h, w2r[ct], s);
        }
        p[reg] = s;
    }
    #pragma unroll
    for (int m = 1; m < 16; m <<= 1) {
        #pragma unroll
        for (int reg = 0; reg < 4; ++reg)
            p[reg] += __shfl_xor(p[reg], m, 64);
    }
    // redistribute: lane l gets score of chunk-row (l&15)
    int r3 = lane & 3;
    float pr = p[0];
    pr = (r3 == 1) ? p[1] : pr;
    pr = (r3 == 2) ? p[2] : pr;
    pr = (r3 == 3) ? p[3] : pr;
    int src = ((lane & 12) << 2) + r3;
    float sv = __shfl(pr, src, 64);      // b2 dropped: softmax shift-invariant

    float s_l = (lr < cv) ? sv : -INFINITY;

    // T13 defer-max: cross-lane max only when reference exceeded
    if (!__all(s_l - r_ref <= 8.f)) {
        float m_c = s_l;
        #pragma unroll
        for (int o = 1; o < 16; o <<= 1) m_c = fmaxf(m_c, __shfl_xor(m_c, o, 64));
        float r_new = fmaxf(r_ref, m_c);
        float scl = __expf(r_ref - r_new);   // 0 when r_ref=-inf
        Sp *= scl;
        #pragma unroll
        for (int kc = 0; kc < 4; ++kc)
            #pragma unroll
            for (int k = 0; k < 8; ++k) pool[kc][k] *= scl;
        r_ref = r_new;
    }
    float w_l = __expf(s_l - r_ref);     // <= e^8; 0 on invalid rows (row lr's weight)
    Sp += w_l;

    // pool: lane (lr,lg) holds row lr cols kc*32+lg*8..+8 in a[kc] — in-register
    #pragma unroll
    for (int kc = 0; kc < 4; ++kc) {
        FragU fa; fa.v = a[kc];
        #pragma unroll
        for (int i = 0; i < 4; ++i) {
            float2 e = __bfloat1622float2(fa.h[i]);
            pool[kc][2 * i]     = fmaf(w_l, e.x, pool[kc][2 * i]);
            pool[kc][2 * i + 1] = fmaf(w_l, e.y, pool[kc][2 * i + 1]);
        }
    }
}

// ---- finalize one segment: reduce Sp + pool over the 16 lr-lanes, write out
static __device__ __forceinline__ void seg_finalize(
        int seg, int lane, int lr, int lg, float r_ref, float Sp,
        float (&pool)[4][8], float* __restrict__ mArr, float* __restrict__ sArr,
        float* __restrict__ tvec) {
    #pragma unroll
    for (int o = 1; o < 16; o <<= 1) Sp += __shfl_xor(Sp, o, 64);
    #pragma unroll
    for (int o = 1; o < 16; o <<= 1) {
        #pragma unroll
        for (int kc = 0; kc < 4; ++kc)
            #pragma unroll
            for (int k = 0; k < 8; ++k)
                pool[kc][k] += __shfl_xor(pool[kc][k], o, 64);
    }
    if (lr == 0) {
        float* tb = &tvec[(long)seg * DIM + lg * 8];
        #pragma unroll
        for (int kc = 0; kc < 4; ++kc) {
            *(float4*)(tb + kc * 32)     = make_float4(pool[kc][0], pool[kc][1], pool[kc][2], pool[kc][3]);
            *(float4*)(tb + kc * 32 + 4) = make_float4(pool[kc][4], pool[kc][5], pool[kc][6], pool[kc][7]);
        }
    }
    if (lane == 0) { mArr[seg] = r_ref; sArr[seg] = Sp; }
}

// ------- Phase 1 (fused; R15 structure, allocator PINNED at 2 waves/SIMD so the
// 232-VGPR working set (bfrag 128 + pool 32 + acc 32 + misc) is NOT spilled)
__global__ __launch_bounds__(256)
__attribute__((amdgpu_waves_per_eu(2, 2)))
void fused_kernel(
        const float* __restrict__ emb, const float* __restrict__ W1,
        const float* __restrict__ b1, const float* __restrict__ W2,
        const float* __restrict__ b2, const int* __restrict__ offsets,
        const int* __restrict__ lengths, int batch, int T,
        const int* __restrict__ uniflag,
        float* __restrict__ mArr, float* __restrict__ sArr,
        float* __restrict__ tvec) {
    __shared__ __align__(16) char smem[65536];

    int tid = threadIdx.x;
    int lane = tid & 63;
    int wv = tid >> 6;
    int lr = lane & 15;
    int lg = lane >> 4;

    // ---- init: stage W1^T (bf16, swizzled) into smem, load B-frags to regs
    ushort* sB = (ushort*)smem;
    for (int i = 0; i < 16; ++i) {
        int q = tid + i * 256;
        int n = q >> 5;
        int k4 = q & 31;
        ushort4 w;
        w.x = f2bf(W1[(k4 * 4 + 0) * DIM + n]);
        w.y = f2bf(W1[(k4 * 4 + 1) * DIM + n]);
        w.z = f2bf(W1[(k4 * 4 + 2) * DIM + n]);
        w.w = f2bf(W1[(k4 * 4 + 3) * DIM + n]);
        int c = k4 >> 1;
        int a16 = n * 128 + ((c ^ (n & 7)) * 8) + (k4 & 1) * 4;
        *(ushort4*)&sB[a16] = w;
    }
    __syncthreads();
    bf16x8 bfrag[8][4];
    #pragma unroll
    for (int ct = 0; ct < 8; ++ct) {
        int n = ct * 16 + lr;
        #pragma unroll
        for (int kc = 0; kc < 4; ++kc) {
            int c = lg + kc * 4;
            bfrag[ct][kc] = *(const bf16x8*)&sB[n * 128 + ((c ^ (n & 7)) * 8)];
        }
    }
    float b1r[8], w2r[8];
    #pragma unroll
    for (int ct = 0; ct < 8; ++ct) {
        b1r[ct] = b1[ct * 16 + lr];
        w2r[ct] = W2[ct * 16 + lr];
    }
    __syncthreads();   // all B-frag reads done; smem now wave-private buffers

    float* buf0 = (float*)(smem + wv * 16384);
    float* buf1 = (float*)(smem + wv * 16384 + 8192);

    long Tm1 = (long)T - 1;
    int nwaves = gridDim.x * 4;
    int gwave = blockIdx.x * 4 + wv;
    int per = (batch + nwaves - 1) / nwaves;
    int seg0 = gwave * per;
    int segend = seg0 + per; if (segend > batch) segend = batch;
    if (seg0 >= segend) return;

    int uni = __builtin_amdgcn_readfirstlane(uniflag[0]);

    if (uni) {
        // ---- fast path: uniform L; stage cursor pure arithmetic, pipelined
        //      across segment boundaries; vmcnt(0) only at the very last chunk.
        int L = __builtin_amdgcn_readfirstlane(lengths[0]);
        int nch = (L + 15) >> 4;
        int ss = seg0, sc = 0;
        #pragma unroll
        for (int k = 0; k < 2; ++k) {
            if (ss < segend) {
                stage16(k ? buf1 : buf0, emb, (long)ss * L + sc * 16, Tm1, lane);
                if (++sc == nch) { sc = 0; ++ss; }
            }
        }
        int cur = 0;
        for (int seg = seg0; seg < segend; ++seg) {
            float r_ref = -INFINITY, Sp = 0.f;
            float pool[4][8];
            #pragma unroll
            for (int kc = 0; kc < 4; ++kc)
                #pragma unroll
                for (int k = 0; k < 8; ++k) pool[kc][k] = 0.f;

            for (int c = 0; c < nch; ++c) {
                if (seg == segend - 1 && c == nch - 1)
                    asm volatile("s_waitcnt vmcnt(0)" ::: "memory");
                else
                    asm volatile("s_waitcnt vmcnt(8)" ::: "memory");
                float* bufc = cur ? buf1 : buf0;
                long stage_row = -1;
                if (ss < segend) {
                    stage_row = (long)ss * L + sc * 16;
                    if (++sc == nch) { sc = 0; ++ss; }
                }
                chunk_body(bufc, L - c * 16, lane, lr, lg, stage_row, emb, Tm1,
                           bfrag, b1r, w2r, r_ref, Sp, pool);
                cur ^= 1;
            }
            seg_finalize(seg, lane, lr, lg, r_ref, Sp, pool, mArr, sArr, tvec);
        }
    } else {
        // ---- fallback: per-segment staging (R8 structure, same chunk body)
        for (int seg = seg0; seg < segend; ++seg) {
            long off = offsets[seg];
            int len = lengths[seg];
            int nch = (len + 15) >> 4;
            float r_ref = -INFINITY, Sp = 0.f;
            float pool[4][8];
            #pragma unroll
            for (int kc = 0; kc < 4; ++kc)
                #pragma unroll
                for (int k = 0; k < 8; ++k) pool[kc][k] = 0.f;

            if (nch > 0) stage16(buf0, emb, off, Tm1, lane);
            if (nch > 1) stage16(buf1, emb, off + 16, Tm1, lane);

            for (int c = 0; c < nch; ++c) {
                float* bufc = (c & 1) ? buf1 : buf0;
                if (c + 1 < nch) asm volatile("s_waitcnt vmcnt(8)" ::: "memory");
                else             asm volatile("s_waitcnt vmcnt(0)" ::: "memory");
                long stage_row = (c + 2 < nch) ? (off + (long)(c + 2) * 16) : -1;
                chunk_body(bufc, len - c * 16, lane, lr, lg, stage_row, emb, Tm1,
                           bfrag, b1r, w2r, r_ref, Sp, pool);
            }
            seg_finalize(seg, lane, lr, lg, r_ref, Sp, pool, mArr, sArr, tvec);
        }
    }
}

// ---------------- Phase 2: global M, 1/S from per-segment (r_b, S'_b) ----------
__global__ __launch_bounds__(1024) void segreduce_kernel(const float* __restrict__ mArr,
        const float* __restrict__ sArr, int batch, float* __restrict__ stats) {
    __shared__ float redm[16], reds[16];
    int tid = threadIdx.x;
    int wave = tid >> 6, ln = tid & 63;
    float m = -INFINITY;
    for (int i = tid; i < batch; i += 1024) m = fmaxf(m, mArr[i]);
    #pragma unroll
    for (int o = 32; o >= 1; o >>= 1) m = fmaxf(m, __shfl_xor(m, o, 64));
    if (ln == 0) redm[wave] = m;
    __syncthreads();
    float M = -INFINITY;
    #pragma unroll
    for (int k = 0; k < 16; ++k) M = fmaxf(M, redm[k]);
    float s = 0.f;
    for (int i = tid; i < batch; i += 1024) s += sArr[i] * expf(mArr[i] - M);
    #pragma unroll
    for (int o = 32; o >= 1; o >>= 1) s += __shfl_xor(s, o, 64);
    if (ln == 0) reds[wave] = s;
    __syncthreads();
    if (tid == 0) {
        float S = 0.f;
        #pragma unroll
        for (int k = 0; k < 16; ++k) S += reds[k];
        stats[0] = M;
        stats[1] = 1.0f / S;
    }
}

// ---------------- Phase 3: out[b][d] = t_b[d] * exp(r_b - M) / S ----------------
__global__ __launch_bounds__(256) void scale_kernel(const float* __restrict__ tvec,
        const float* __restrict__ mArr, const float* __restrict__ stats,
        float* __restrict__ out, int n) {
    int idx = blockIdx.x * 256 + threadIdx.x;
    if (idx >= n) return;
    float M = stats[0], invS = stats[1];
    int b = idx >> 7;
    out[idx] = tvec[idx] * (expf(mArr[b] - M) * invS);
}

extern "C" void kernel_launch(void* const* d_in, const int* in_sizes, int n_in,
                              void* d_out, int out_size, void* d_ws, size_t ws_size,
                              hipStream_t stream) {
    const float* emb     = (const float*)d_in[0];
    const float* W1      = (const float*)d_in[1];
    const float* b1      = (const float*)d_in[2];
    const float* W2      = (const float*)d_in[3];
    const float* b2      = (const float*)d_in[4];
    const int*   lengths = (const int*)d_in[5];
    (void)b2;
    int T = in_sizes[0] / DIM;
    int batch = in_sizes[5];
    float* out = (float*)d_out;

    // ws: offsets[batch] | mArr[batch] | sArr[batch] | stats[2] | uniflag | pad | tvec
    int*   offsets = (int*)d_ws;
    float* mArr    = (float*)(offsets + batch);
    float* sArr    = mArr + batch;
    float* stats   = sArr + batch;
    int*   uniflag = (int*)(stats + 2);
    float* tvec    = stats + 4;

    scan_kernel<<<1, 1024, 0, stream>>>(lengths, offsets, batch, uniflag);
    fused_kernel<<<512, 256, 0, stream>>>(emb, W1, b1, W2, b2, offsets, lengths,
                                          batch, T, uniflag, mArr, sArr, tvec);
    segreduce_kernel<<<1, 1024, 0, stream>>>(mArr, sArr, batch, stats);
    scale_kernel<<<(out_size + 255) / 256, 256, 0, stream>>>(tvec, mArr, stats, out, out_size);
}

// Round 18
// 163.405 us; speedup vs baseline: 1.5388x; 1.5388x over previous
//
#include <hip/hip_runtime.h>
#include <hip/hip_bf16.h>
#include <math.h>

#define DIM 128

typedef __attribute__((ext_vector_type(8))) short bf16x8;
typedef __attribute__((ext_vector_type(4))) float f32x4;

union FragU { bf16x8 v; __hip_bfloat162 h[4]; };

// RNE float -> bf16 bits
static __device__ __forceinline__ ushort f2bf(float f) {
    unsigned u = __float_as_uint(f);
    u += 0x7FFFu + ((u >> 16) & 1u);
    return (ushort)(u >> 16);
}

// async global -> LDS, 16B per lane (lds dest wave-uniform base + lane*16)
typedef __attribute__((address_space(1))) const unsigned GASp;
typedef __attribute__((address_space(3))) unsigned LASp;
static __device__ __forceinline__ void gll16(const void* g, void* l) {
    __builtin_amdgcn_global_load_lds((GASp*)g, (LASp*)l, 16, 0, 0);
}

// stage 16 rows x 128 f32 (8KB); source pre-swizzled: LDS slot (r,x) holds
// emb 16B-chunk (r, x ^ (r&7))
static __device__ __forceinline__ void stage16(float* buf, const float* emb,
                                               long row0, long Tm1, int lane) {
    #pragma unroll
    for (int i = 0; i < 8; ++i) {
        int s = i * 64 + lane;
        int r = s >> 5, x = s & 31;
        long gr = row0 + r; gr = (gr > Tm1) ? Tm1 : gr;
        gll16(emb + gr * 128 + ((x ^ (r & 7)) << 2), (char*)buf + i * 1024);
    }
}

// ---------------- Phase 0: exclusive scan + uniformity flag ----------------
__global__ __launch_bounds__(1024) void scan_kernel(const int* __restrict__ lengths,
                                                    int* __restrict__ offsets, int batch,
                                                    int* __restrict__ uniflag) {
    __shared__ int tsum[1024];
    __shared__ int ok;
    int tid = threadIdx.x;
    if (tid == 0) ok = 1;
    int L0 = lengths[0];
    int per = (batch + 1023) >> 10;
    int start = tid * per;
    int s = 0;
    int loc = 1;
    for (int i = 0; i < per; ++i) {
        int idx = start + i;
        if (idx < batch) {
            int l = lengths[idx];
            s += l;
            if (l != L0) loc = 0;
        }
    }
    tsum[tid] = s;
    __syncthreads();
    if (!loc) atomicAnd(&ok, 0);
    for (int off = 1; off < 1024; off <<= 1) {
        int v = (tid >= off) ? tsum[tid - off] : 0;
        __syncthreads();
        tsum[tid] += v;
        __syncthreads();
    }
    int base = (tid == 0) ? 0 : tsum[tid - 1];
    for (int i = 0; i < per; ++i) {
        int idx = start + i;
        if (idx < batch) { offsets[idx] = base; base += lengths[idx]; }
    }
    __syncthreads();
    if (tid == 0) uniflag[0] = ok;
}

// ---- one 16-row chunk: A-frags -> MFMA -> score epilogue -> defer-max -> pool
static __device__ __forceinline__ void chunk_body(
        const float* __restrict__ bufc, int cv, int lane, int lr, int lg,
        int xc, int xh, const bf16x8 (&bfrag)[8][4],
        const float (&b1r)[8], const float (&w2r)[8],
        float& r_ref, float& Sp, float& t0, float& t1) {
    // A-frags: swizzled ds_read_b128 pairs + cvt to bf16
    bf16x8 a[4];
    #pragma unroll
    for (int kc = 0; kc < 4; ++kc) {
        int c0 = kc * 8 + lg * 2;
        float4 q0 = *(const float4*)&bufc[(lr * 32 + (c0 ^ (lr & 7))) * 4];
        float4 q1 = *(const float4*)&bufc[(lr * 32 + ((c0 + 1) ^ (lr & 7))) * 4];
        FragU f;
        f.h[0] = __float22bfloat162_rn(make_float2(q0.x, q0.y));
        f.h[1] = __float22bfloat162_rn(make_float2(q0.z, q0.w));
        f.h[2] = __float22bfloat162_rn(make_float2(q1.x, q1.y));
        f.h[3] = __float22bfloat162_rn(make_float2(q1.z, q1.w));
        a[kc] = f.v;
    }

    // MFMA: scores for these 16 rows (C: col=lane&15, row=lg*4+reg)
    f32x4 acc[8];
    #pragma unroll
    for (int ct = 0; ct < 8; ++ct) acc[ct] = (f32x4)(0.f);
    #pragma unroll
    for (int ct = 0; ct < 8; ++ct)
        #pragma unroll
        for (int kc = 0; kc < 4; ++kc)
            acc[ct] = __builtin_amdgcn_mfma_f32_16x16x32_bf16(a[kc], bfrag[ct][kc], acc[ct], 0, 0, 0);

    // epilogue: rowsum of relu(acc+b1)*W2 over 16 col-lanes (4 rounds)
    float p[4];
    #pragma unroll
    for (int reg = 0; reg < 4; ++reg) {
        float s = 0.f;
        #pragma unroll
        for (int ct = 0; ct < 8; ++ct) {
            float h = acc[ct][reg] + b1r[ct];
            h = fmaxf(h, 0.f);
            s = fmaf(h, w2r[ct], s);
        }
        p[reg] = s;
    }
    #pragma unroll
    for (int m = 1; m < 16; m <<= 1) {
        #pragma unroll
        for (int reg = 0; reg < 4; ++reg)
            p[reg] += __shfl_xor(p[reg], m, 64);
    }
    // redistribute: lane l gets score of chunk-row (l&15)
    int r3 = lane & 3;
    float pr = p[0];
    pr = (r3 == 1) ? p[1] : pr;
    pr = (r3 == 2) ? p[2] : pr;
    pr = (r3 == 3) ? p[3] : pr;
    int src = ((lane & 12) << 2) + r3;
    float sv = __shfl(pr, src, 64);      // b2 dropped: softmax shift-invariant

    float s_l = (lr < cv) ? sv : -INFINITY;

    // T13 defer-max: cross-lane max only when reference exceeded
    if (!__all(s_l - r_ref <= 8.f)) {
        float m_c = s_l;
        #pragma unroll
        for (int o = 1; o < 16; o <<= 1) m_c = fmaxf(m_c, __shfl_xor(m_c, o, 64));
        float r_new = fmaxf(r_ref, m_c);
        float scl = __expf(r_ref - r_new);   // 0 when r_ref=-inf
        Sp *= scl; t0 *= scl; t1 *= scl;
        r_ref = r_new;
    }
    float w_l = __expf(s_l - r_ref);     // <= e^8; 0 on invalid rows
    Sp += w_l;

    // pool: 4 groups of 4 independent ds_read_b64, then fmas
    #pragma unroll
    for (int jg = 0; jg < 4; ++jg) {
        int j0 = jg * 4;
        float2 e0 = *(const float2*)&bufc[((j0 + 0) * 32 + (xc ^ ((j0 + 0) & 7))) * 4 + xh * 2];
        float2 e1 = *(const float2*)&bufc[((j0 + 1) * 32 + (xc ^ ((j0 + 1) & 7))) * 4 + xh * 2];
        float2 e2 = *(const float2*)&bufc[((j0 + 2) * 32 + (xc ^ ((j0 + 2) & 7))) * 4 + xh * 2];
        float2 e3 = *(const float2*)&bufc[((j0 + 3) * 32 + (xc ^ ((j0 + 3) & 7))) * 4 + xh * 2];
        float w0 = __uint_as_float(__builtin_amdgcn_readlane(__float_as_uint(w_l), j0 + 0));
        float w1v = __uint_as_float(__builtin_amdgcn_readlane(__float_as_uint(w_l), j0 + 1));
        float w2v = __uint_as_float(__builtin_amdgcn_readlane(__float_as_uint(w_l), j0 + 2));
        float w3 = __uint_as_float(__builtin_amdgcn_readlane(__float_as_uint(w_l), j0 + 3));
        t0 = fmaf(w0, e0.x, t0); t1 = fmaf(w0, e0.y, t1);
        t0 = fmaf(w1v, e1.x, t0); t1 = fmaf(w1v, e1.y, t1);
        t0 = fmaf(w2v, e2.x, t0); t1 = fmaf(w2v, e2.y, t1);
        t0 = fmaf(w3, e3.x, t0); t1 = fmaf(w3, e3.y, t1);
    }
}

// ------- Phase 1 (fused; R8 skeleton + cross-segment staging on uniform lengths)
__global__ __launch_bounds__(256, 2) void fused_kernel(
        const float* __restrict__ emb, const float* __restrict__ W1,
        const float* __restrict__ b1, const float* __restrict__ W2,
        const float* __restrict__ b2, const int* __restrict__ offsets,
        const int* __restrict__ lengths, int batch, int T,
        const int* __restrict__ uniflag,
        float* __restrict__ mArr, float* __restrict__ sArr,
        float* __restrict__ tvec) {
    __shared__ __align__(16) char smem[65536];

    int tid = threadIdx.x;
    int lane = tid & 63;
    int wv = tid >> 6;
    int lr = lane & 15;
    int lg = lane >> 4;

    // ---- init: stage W1^T (bf16, swizzled) into smem, load B-frags to regs
    ushort* sB = (ushort*)smem;
    for (int i = 0; i < 16; ++i) {
        int q = tid + i * 256;
        int n = q >> 5;
        int k4 = q & 31;
        ushort4 w;
        w.x = f2bf(W1[(k4 * 4 + 0) * DIM + n]);
        w.y = f2bf(W1[(k4 * 4 + 1) * DIM + n]);
        w.z = f2bf(W1[(k4 * 4 + 2) * DIM + n]);
        w.w = f2bf(W1[(k4 * 4 + 3) * DIM + n]);
        int c = k4 >> 1;
        int a16 = n * 128 + ((c ^ (n & 7)) * 8) + (k4 & 1) * 4;
        *(ushort4*)&sB[a16] = w;
    }
    __syncthreads();
    bf16x8 bfrag[8][4];
    #pragma unroll
    for (int ct = 0; ct < 8; ++ct) {
        int n = ct * 16 + lr;
        #pragma unroll
        for (int kc = 0; kc < 4; ++kc) {
            int c = lg + kc * 4;
            bfrag[ct][kc] = *(const bf16x8*)&sB[n * 128 + ((c ^ (n & 7)) * 8)];
        }
    }
    float b1r[8], w2r[8];
    #pragma unroll
    for (int ct = 0; ct < 8; ++ct) {
        b1r[ct] = b1[ct * 16 + lr];
        w2r[ct] = W2[ct * 16 + lr];
    }
    __syncthreads();   // all B-frag reads done; smem now wave-private buffers

    float* buf0 = (float*)(smem + wv * 16384);
    float* buf1 = (float*)(smem + wv * 16384 + 8192);

    long Tm1 = (long)T - 1;
    int nwaves = gridDim.x * 4;
    int gwave = blockIdx.x * 4 + wv;
    int per = (batch + nwaves - 1) / nwaves;
    int seg0 = gwave * per;
    int segend = seg0 + per; if (segend > batch) segend = batch;
    if (seg0 >= segend) return;

    int xc = lane >> 1, xh = lane & 1;
    int uni = __builtin_amdgcn_readfirstlane(uniflag[0]);

    if (uni) {
        // ---- fast path: uniform L; stage cursor is pure arithmetic (SGPRs),
        //      pipelined ACROSS segment boundaries; one vmcnt(0) at the very end.
        int L = __builtin_amdgcn_readfirstlane(lengths[0]);
        int nch = (L + 15) >> 4;
        int ss = seg0, sc = 0;
        #pragma unroll
        for (int k = 0; k < 2; ++k) {
            if (ss < segend) {
                stage16(k ? buf1 : buf0, emb, (long)ss * L + sc * 16, Tm1, lane);
                if (++sc == nch) { sc = 0; ++ss; }
            }
        }
        int cur = 0;
        for (int seg = seg0; seg < segend; ++seg) {
            float r_ref = -INFINITY, Sp = 0.f, t0 = 0.f, t1 = 0.f;
            for (int c = 0; c < nch; ++c) {
                if (seg == segend - 1 && c == nch - 1)
                    asm volatile("s_waitcnt vmcnt(0)" ::: "memory");
                else
                    asm volatile("s_waitcnt vmcnt(8)" ::: "memory");
                float* bufc = cur ? buf1 : buf0;
                chunk_body(bufc, L - c * 16, lane, lr, lg, xc, xh,
                           bfrag, b1r, w2r, r_ref, Sp, t0, t1);
                // pool ds_reads done -> restage with the next pending chunk
                asm volatile("s_waitcnt lgkmcnt(0)" ::: "memory");
                if (ss < segend) {
                    stage16(bufc, emb, (long)ss * L + sc * 16, Tm1, lane);
                    if (++sc == nch) { sc = 0; ++ss; }
                }
                cur ^= 1;
            }
            #pragma unroll
            for (int o = 1; o < 16; o <<= 1) Sp += __shfl_xor(Sp, o, 64);
            *(float2*)&tvec[(long)seg * DIM + 2 * lane] = make_float2(t0, t1);
            if (lane == 0) { mArr[seg] = r_ref; sArr[seg] = Sp; }
        }
    } else {
        // ---- fallback: exact R8 structure (per-segment staging)
        for (int seg = seg0; seg < segend; ++seg) {
            long off = offsets[seg];
            int len = lengths[seg];
            int nch = (len + 15) >> 4;
            float r_ref = -INFINITY, Sp = 0.f, t0 = 0.f, t1 = 0.f;

            if (nch > 0) stage16(buf0, emb, off, Tm1, lane);
            if (nch > 1) stage16(buf1, emb, off + 16, Tm1, lane);

            for (int c = 0; c < nch; ++c) {
                float* bufc = (c & 1) ? buf1 : buf0;
                if (c + 1 < nch) asm volatile("s_waitcnt vmcnt(8)" ::: "memory");
                else             asm volatile("s_waitcnt vmcnt(0)" ::: "memory");
                chunk_body(bufc, len - c * 16, lane, lr, lg, xc, xh,
                           bfrag, b1r, w2r, r_ref, Sp, t0, t1);
                asm volatile("s_waitcnt lgkmcnt(0)" ::: "memory");
                if (c + 2 < nch) stage16(bufc, emb, off + (long)(c + 2) * 16, Tm1, lane);
            }
            #pragma unroll
            for (int o = 1; o < 16; o <<= 1) Sp += __shfl_xor(Sp, o, 64);
            *(float2*)&tvec[(long)seg * DIM + 2 * lane] = make_float2(t0, t1);
            if (lane == 0) { mArr[seg] = r_ref; sArr[seg] = Sp; }
        }
    }
}

// ---------------- Phase 2: global M, 1/S from per-segment (r_b, S'_b) ----------
__global__ __launch_bounds__(1024) void segreduce_kernel(const float* __restrict__ mArr,
        const float* __restrict__ sArr, int batch, float* __restrict__ stats) {
    __shared__ float redm[16], reds[16];
    int tid = threadIdx.x;
    int wave = tid >> 6, ln = tid & 63;
    float m = -INFINITY;
    for (int i = tid; i < batch; i += 1024) m = fmaxf(m, mArr[i]);
    #pragma unroll
    for (int o = 32; o >= 1; o >>= 1) m = fmaxf(m, __shfl_xor(m, o, 64));
    if (ln == 0) redm[wave] = m;
    __syncthreads();
    float M = -INFINITY;
    #pragma unroll
    for (int k = 0; k < 16; ++k) M = fmaxf(M, redm[k]);
    float s = 0.f;
    for (int i = tid; i < batch; i += 1024) s += sArr[i] * expf(mArr[i] - M);
    #pragma unroll
    for (int o = 32; o >= 1; o >>= 1) s += __shfl_xor(s, o, 64);
    if (ln == 0) reds[wave] = s;
    __syncthreads();
    if (tid == 0) {
        float S = 0.f;
        #pragma unroll
        for (int k = 0; k < 16; ++k) S += reds[k];
        stats[0] = M;
        stats[1] = 1.0f / S;
    }
}

// ---------------- Phase 3: out[b][d] = t_b[d] * exp(r_b - M) / S ----------------
__global__ __launch_bounds__(256) void scale_kernel(const float* __restrict__ tvec,
        const float* __restrict__ mArr, const float* __restrict__ stats,
        float* __restrict__ out, int n) {
    int idx = blockIdx.x * 256 + threadIdx.x;
    if (idx >= n) return;
    float M = stats[0], invS = stats[1];
    int b = idx >> 7;
    out[idx] = tvec[idx] * (expf(mArr[b] - M) * invS);
}

extern "C" void kernel_launch(void* const* d_in, const int* in_sizes, int n_in,
                              void* d_out, int out_size, void* d_ws, size_t ws_size,
                              hipStream_t stream) {
    const float* emb     = (const float*)d_in[0];
    const float* W1      = (const float*)d_in[1];
    const float* b1      = (const float*)d_in[2];
    const float* W2      = (const float*)d_in[3];
    const float* b2      = (const float*)d_in[4];
    const int*   lengths = (const int*)d_in[5];
    int T = in_sizes[0] / DIM;
    int batch = in_sizes[5];
    float* out = (float*)d_out;

    // ws: offsets[batch] | mArr[batch] | sArr[batch] | stats[2] | uniflag | pad | tvec
    int*   offsets = (int*)d_ws;
    float* mArr    = (float*)(offsets + batch);
    float* sArr    = mArr + batch;
    float* stats   = sArr + batch;
    int*   uniflag = (int*)(stats + 2);
    float* tvec    = stats + 4;

    scan_kernel<<<1, 1024, 0, stream>>>(lengths, offsets, batch, uniflag);
    fused_kernel<<<512, 256, 0, stream>>>(emb, W1, b1, W2, b2, offsets, lengths,
                                          batch, T, uniflag, mArr, sArr, tvec);
    segreduce_kernel<<<1, 1024, 0, stream>>>(mArr, sArr, batch, stats);
    scale_kernel<<<(out_size + 255) / 256, 256, 0, stream>>>(tvec, mArr, stats, out, out_size);
}